// Round 1
// baseline (3387.533 us; speedup 1.0000x reference)
//
#include <hip/hip_runtime.h>

// GATConv with edge features, MI355X fp32 implementation.
// F_IN = 128, H*D = 128, E = 800000, N = 50000.
//
// Algebra: m = src_proj[src] + edge_feat @ W_bot  (src_proj precomputed per node)
//          rst = (sum_e exp(leaky(m+nh[dst])) * m) / (sum_e exp(leaky(m+nh[dst]))) + bias
// (max-free softmax: scores are O(12), exp fits fp32 easily; single edge pass, m never stored)

#define F 128      // F_IN
#define C 128      // H*D
#define NEG 0.2f

__device__ __forceinline__ void fma4(float4& a, float s, const float4 w) {
    a.x += s * w.x; a.y += s * w.y; a.z += s * w.z; a.w += s * w.w;
}

// ---------------- node projection: out[n][j] = sum_k in[n][k] * W[k][j]
// grid = (N/8, 2), block = 256.  y==0: src_feat@W_src_top -> src_proj ; y==1: dst_feat@W_dst -> nh
__global__ __launch_bounds__(256) void node_proj_kernel(
    const float* __restrict__ src_feat, const float* __restrict__ dst_feat,
    const float* __restrict__ W_src, const float* __restrict__ W_dst,
    float* __restrict__ src_proj, float* __restrict__ nh)
{
    const float* in; const float* W; float* out;
    if (blockIdx.y == 0) { in = src_feat; W = W_src; out = src_proj; }
    else                 { in = dst_feat; W = W_dst; out = nh; }

    __shared__ float4 xs[8 * 32];   // 8 rows x 128 floats
    const int t  = threadIdx.x;
    const int nb = blockIdx.x * 8;

    // stage 8 input rows (256 float4, one per thread)
    {
        int row = t >> 5, col = t & 31;
        xs[t] = ((const float4*)(in + (size_t)(nb + row) * F))[col];
    }
    __syncthreads();

    const int jq = t & 31;   // channel quad: j0 = 4*jq
    const int ng = t >> 5;   // node within tile
    float4 acc = make_float4(0.f, 0.f, 0.f, 0.f);
    const float4* W4 = (const float4*)W;

    #pragma unroll 4
    for (int k4 = 0; k4 < 32; ++k4) {
        float4 xv = xs[ng * 32 + k4];
        float4 w0 = W4[(4 * k4 + 0) * 32 + jq];
        float4 w1 = W4[(4 * k4 + 1) * 32 + jq];
        float4 w2 = W4[(4 * k4 + 2) * 32 + jq];
        float4 w3 = W4[(4 * k4 + 3) * 32 + jq];
        fma4(acc, xv.x, w0); fma4(acc, xv.y, w1);
        fma4(acc, xv.z, w2); fma4(acc, xv.w, w3);
    }
    ((float4*)(out + (size_t)(nb + ng) * C))[jq] = acc;
}

// ---------------- edge pass: per-edge GEMM + gather + exp + atomic num/den
// grid = E/64, block = 256. Tile: 64 edges x 128 channels; per thread 8 edges x 4 channels.
__global__ __launch_bounds__(256) void edge_kernel(
    const float* __restrict__ edge_feat, const float* __restrict__ Wb,   // W_src + 128*128
    const float* __restrict__ src_proj, const float* __restrict__ nh,
    const int* __restrict__ src_idx, const int* __restrict__ dst_idx,
    float* __restrict__ num, float* __restrict__ den)
{
    __shared__ float4 xs[64 * 32];   // 64 edge rows x 128 floats = 32 KB
    __shared__ int sidx[64];
    __shared__ int didx[64];

    const int t  = threadIdx.x;
    const int eb = blockIdx.x * 64;

    // stage 64 edge rows: 2048 float4, 8 per thread (coalesced)
    #pragma unroll
    for (int i = 0; i < 8; ++i) {
        int flat = t + i * 256;
        int row = flat >> 5, col = flat & 31;
        xs[flat] = ((const float4*)(edge_feat + (size_t)(eb + row) * F))[col];
    }
    if (t < 64) { sidx[t] = src_idx[eb + t]; didx[t] = dst_idx[eb + t]; }
    __syncthreads();

    const int jq = t & 31;   // channel quad: j0 = 4*jq
    const int eg = t >> 5;   // edge group 0..7 -> edges eg*8 .. eg*8+7

    float4 acc[8];
    #pragma unroll
    for (int i = 0; i < 8; ++i) acc[i] = make_float4(0.f, 0.f, 0.f, 0.f);

    const float4* W4 = (const float4*)Wb;

    #pragma unroll 2
    for (int k4 = 0; k4 < 32; ++k4) {
        float4 w0 = W4[(4 * k4 + 0) * 32 + jq];
        float4 w1 = W4[(4 * k4 + 1) * 32 + jq];
        float4 w2 = W4[(4 * k4 + 2) * 32 + jq];
        float4 w3 = W4[(4 * k4 + 3) * 32 + jq];
        #pragma unroll
        for (int i = 0; i < 8; ++i) {
            float4 xv = xs[(eg * 8 + i) * 32 + k4];   // 32-lane broadcast
            fma4(acc[i], xv.x, w0); fma4(acc[i], xv.y, w1);
            fma4(acc[i], xv.z, w2); fma4(acc[i], xv.w, w3);
        }
    }

    // epilogue: m = acc + src_proj[src];  s = leaky(m + nh[dst]);  ex = exp(s)
    // num[dst] += ex*m ; den[dst] += ex
    #pragma unroll
    for (int i = 0; i < 8; ++i) {
        int e  = eg * 8 + i;
        int se = sidx[e];
        int de = didx[e];
        float4 sp = ((const float4*)(src_proj + (size_t)se * C))[jq];
        float4 nv = ((const float4*)(nh       + (size_t)de * C))[jq];

        float m0 = acc[i].x + sp.x, m1 = acc[i].y + sp.y;
        float m2 = acc[i].z + sp.z, m3 = acc[i].w + sp.w;

        float s0 = m0 + nv.x, s1 = m1 + nv.y, s2 = m2 + nv.z, s3 = m3 + nv.w;
        s0 = s0 > 0.f ? s0 : NEG * s0;
        s1 = s1 > 0.f ? s1 : NEG * s1;
        s2 = s2 > 0.f ? s2 : NEG * s2;
        s3 = s3 > 0.f ? s3 : NEG * s3;

        float e0 = __expf(s0), e1 = __expf(s1), e2 = __expf(s2), e3 = __expf(s3);

        float* np = num + (size_t)de * C + jq * 4;
        float* dp = den + (size_t)de * C + jq * 4;
        atomicAdd(np + 0, e0 * m0);
        atomicAdd(np + 1, e1 * m1);
        atomicAdd(np + 2, e2 * m2);
        atomicAdd(np + 3, e3 * m3);
        atomicAdd(dp + 0, e0);
        atomicAdd(dp + 1, e1);
        atomicAdd(dp + 2, e2);
        atomicAdd(dp + 3, e3);
    }
}

// ---------------- finalize: out = num/den + bias  (den==0 -> bias, matches empty segment)
__global__ __launch_bounds__(256) void finalize_kernel(
    const float* __restrict__ num, const float* __restrict__ den,
    const float* __restrict__ bias, float* __restrict__ out)
{
    int i = blockIdx.x * 256 + threadIdx.x;      // float4 index
    float4 n = ((const float4*)num)[i];
    float4 d = ((const float4*)den)[i];
    float4 b = ((const float4*)bias)[i & 31];
    float4 r;
    r.x = (d.x != 0.f ? n.x / d.x : 0.f) + b.x;
    r.y = (d.y != 0.f ? n.y / d.y : 0.f) + b.y;
    r.z = (d.z != 0.f ? n.z / d.z : 0.f) + b.z;
    r.w = (d.w != 0.f ? n.w / d.w : 0.f) + b.w;
    ((float4*)out)[i] = r;
}

extern "C" void kernel_launch(void* const* d_in, const int* in_sizes, int n_in,
                              void* d_out, int out_size, void* d_ws, size_t ws_size,
                              hipStream_t stream) {
    const float* src_feat  = (const float*)d_in[0];
    const float* dst_feat  = (const float*)d_in[1];
    const float* edge_feat = (const float*)d_in[2];
    const float* W_src     = (const float*)d_in[3];   // [256][128]
    const float* W_dst     = (const float*)d_in[4];   // [128][128]
    const float* bias      = (const float*)d_in[5];   // [128]
    const int*   src_idx   = (const int*)d_in[6];
    const int*   dst_idx   = (const int*)d_in[7];
    float* out = (float*)d_out;                       // [50000][128] -> doubles as num accumulator

    const int N = 50000;
    const int E = 800000;
    const size_t NODEF = (size_t)N * C;               // 6.4M floats

    float* ws       = (float*)d_ws;
    float* src_proj = ws;                             // 6.4M floats
    float* nh       = ws + NODEF;                     // 6.4M floats
    float* den      = ws + 2 * NODEF;                 // 6.4M floats   (76.8 MB total)

    float* num = out;  // accumulate numerator directly in d_out, finalize in place

    hipMemsetAsync(num, 0, NODEF * sizeof(float), stream);
    hipMemsetAsync(den, 0, NODEF * sizeof(float), stream);

    node_proj_kernel<<<dim3(N / 8, 2), 256, 0, stream>>>(
        src_feat, dst_feat, W_src, W_dst, src_proj, nh);

    edge_kernel<<<E / 64, 256, 0, stream>>>(
        edge_feat, W_src + 128 * 128, src_proj, nh, src_idx, dst_idx, num, den);

    finalize_kernel<<<NODEF / 4 / 256, 256, 0, stream>>>(num, den, bias, out);
}

// Round 2
// 1412.368 us; speedup vs baseline: 2.3985x; 2.3985x over previous
//
#include <hip/hip_runtime.h>

// GATConv with edge features, MI355X fp32. Round 2: dst-sorted edge processing.
//
// R1 post-mortem: edge kernel was atomic-bound (205M scattered f32 atomics,
// WRITE_SIZE 3.2GB, VALUBusy 8%). Fix: sort edges by dst (hist+scan+scatter),
// run the tiled edge GEMM in sorted order, run-compress atomics per thread.
//
// Algebra: m = src_proj[src] + edge_feat @ W_bot  (src_proj per node, not per edge)
//          rst = (sum_e exp(leaky(m+nh[dst])) * m) / (sum_e exp(leaky(m+nh[dst]))) + bias
// (max-free softmax: scores are O(12), exp fits fp32; single edge pass, m never stored)

#define F 128      // F_IN
#define C 128      // H*D
#define NEG 0.2f
#define NN 50000
#define EE 800000

__device__ __forceinline__ void fma4(float4& a, float s, const float4 w) {
    a.x += s * w.x; a.y += s * w.y; a.z += s * w.z; a.w += s * w.w;
}

// ---------------- node projection: out[n][j] = sum_k in[n][k] * W[k][j]
// grid = (N/8, 2), block = 256.  y==0: src_feat@W_src_top -> src_proj ; y==1: dst_feat@W_dst -> nh
__global__ __launch_bounds__(256) void node_proj_kernel(
    const float* __restrict__ src_feat, const float* __restrict__ dst_feat,
    const float* __restrict__ W_src, const float* __restrict__ W_dst,
    float* __restrict__ src_proj, float* __restrict__ nh)
{
    const float* in; const float* W; float* out;
    if (blockIdx.y == 0) { in = src_feat; W = W_src; out = src_proj; }
    else                 { in = dst_feat; W = W_dst; out = nh; }

    __shared__ float4 xs[8 * 32];   // 8 rows x 128 floats
    const int t  = threadIdx.x;
    const int nb = blockIdx.x * 8;

    {
        int row = t >> 5, col = t & 31;
        xs[t] = ((const float4*)(in + (size_t)(nb + row) * F))[col];
    }
    __syncthreads();

    const int jq = t & 31;
    const int ng = t >> 5;
    float4 acc = make_float4(0.f, 0.f, 0.f, 0.f);
    const float4* W4 = (const float4*)W;

    #pragma unroll 4
    for (int k4 = 0; k4 < 32; ++k4) {
        float4 xv = xs[ng * 32 + k4];
        float4 w0 = W4[(4 * k4 + 0) * 32 + jq];
        float4 w1 = W4[(4 * k4 + 1) * 32 + jq];
        float4 w2 = W4[(4 * k4 + 2) * 32 + jq];
        float4 w3 = W4[(4 * k4 + 3) * 32 + jq];
        fma4(acc, xv.x, w0); fma4(acc, xv.y, w1);
        fma4(acc, xv.z, w2); fma4(acc, xv.w, w3);
    }
    ((float4*)(out + (size_t)(nb + ng) * C))[jq] = acc;
}

// ---------------- sort-by-dst machinery ----------------
__global__ __launch_bounds__(256) void hist_kernel(
    const int* __restrict__ dst_idx, int* __restrict__ deg)
{
    int e = blockIdx.x * 256 + threadIdx.x;
    if (e < EE) atomicAdd(&deg[dst_idx[e]], 1);
}

// exclusive prefix sum of deg[NN] -> cursor[NN]; single block of 1024 threads
__global__ __launch_bounds__(1024) void scan_kernel(
    const int* __restrict__ deg, int* __restrict__ cursor)
{
    __shared__ int ssum[1024];
    const int t = threadIdx.x;
    const int chunk = (NN + 1023) / 1024;   // 49
    int lo = t * chunk, hi = lo + chunk; if (hi > NN) hi = NN; if (lo > NN) lo = NN;
    int s = 0;
    for (int i = lo; i < hi; ++i) s += deg[i];
    ssum[t] = s;
    __syncthreads();
    for (int d = 1; d < 1024; d <<= 1) {
        int v = (t >= d) ? ssum[t - d] : 0;
        __syncthreads();
        ssum[t] += v;
        __syncthreads();
    }
    int run = ssum[t] - s;   // exclusive base
    for (int i = lo; i < hi; ++i) { cursor[i] = run; run += deg[i]; }
}

__global__ __launch_bounds__(256) void scatter_kernel(
    const int* __restrict__ dst_idx, int* __restrict__ cursor, int* __restrict__ elist)
{
    int e = blockIdx.x * 256 + threadIdx.x;
    if (e < EE) {
        int p = atomicAdd(&cursor[dst_idx[e]], 1);
        elist[p] = e;
    }
}

// ---------------- edge pass over SORTED edges: GEMM + gather + exp + run-compressed atomics
// grid = E/64, block = 256. Tile: 64 edges x 128 channels; per thread 8 edges x 4 channels.
__global__ __launch_bounds__(256) void edge_kernel(
    const float* __restrict__ edge_feat, const float* __restrict__ Wb,   // W_src + 128*128
    const float* __restrict__ src_proj, const float* __restrict__ nh,
    const int* __restrict__ src_idx, const int* __restrict__ dst_idx,
    const int* __restrict__ elist,
    float* __restrict__ num, float* __restrict__ den)
{
    __shared__ float4 xs[64 * 32];   // 64 edge rows x 128 floats = 32 KB
    __shared__ int sidx[64];
    __shared__ int didx[64];
    __shared__ int es[64];

    const int t  = threadIdx.x;
    const int eb = blockIdx.x * 64;

    if (t < 64) {
        int e = elist[eb + t];
        es[t] = e;
        sidx[t] = src_idx[e];
        didx[t] = dst_idx[e];
    }
    __syncthreads();

    // stage 64 sorted edge rows: 2048 float4, 8 per thread (coalesced within each row)
    #pragma unroll
    for (int i = 0; i < 8; ++i) {
        int flat = t + i * 256;
        int row = flat >> 5, col = flat & 31;
        xs[flat] = ((const float4*)(edge_feat + (size_t)es[row] * F))[col];
    }
    __syncthreads();

    const int jq = t & 31;   // channel quad: j0 = 4*jq
    const int eg = t >> 5;   // edge group 0..7 -> edges eg*8 .. eg*8+7

    float4 acc[8];
    #pragma unroll
    for (int i = 0; i < 8; ++i) acc[i] = make_float4(0.f, 0.f, 0.f, 0.f);

    const float4* W4 = (const float4*)Wb;

    #pragma unroll 2
    for (int k4 = 0; k4 < 32; ++k4) {
        float4 w0 = W4[(4 * k4 + 0) * 32 + jq];
        float4 w1 = W4[(4 * k4 + 1) * 32 + jq];
        float4 w2 = W4[(4 * k4 + 2) * 32 + jq];
        float4 w3 = W4[(4 * k4 + 3) * 32 + jq];
        #pragma unroll
        for (int i = 0; i < 8; ++i) {
            float4 xv = xs[(eg * 8 + i) * 32 + k4];   // 32-lane broadcast
            fma4(acc[i], xv.x, w0); fma4(acc[i], xv.y, w1);
            fma4(acc[i], xv.z, w2); fma4(acc[i], xv.w, w3);
        }
    }

    // epilogue: edges sorted by dst -> run-compress the atomic accumulation
    int cur = didx[eg * 8];
    float4 nv = ((const float4*)(nh + (size_t)cur * C))[jq];
    float4 nacc = make_float4(0.f, 0.f, 0.f, 0.f);
    float4 dacc = make_float4(0.f, 0.f, 0.f, 0.f);

    #pragma unroll
    for (int i = 0; i < 8; ++i) {
        int el = eg * 8 + i;
        int d  = didx[el];
        if (d != cur) {
            float* np = num + (size_t)cur * C + jq * 4;
            float* dp = den + (size_t)cur * C + jq * 4;
            atomicAdd(np + 0, nacc.x); atomicAdd(np + 1, nacc.y);
            atomicAdd(np + 2, nacc.z); atomicAdd(np + 3, nacc.w);
            atomicAdd(dp + 0, dacc.x); atomicAdd(dp + 1, dacc.y);
            atomicAdd(dp + 2, dacc.z); atomicAdd(dp + 3, dacc.w);
            nacc = make_float4(0.f, 0.f, 0.f, 0.f);
            dacc = make_float4(0.f, 0.f, 0.f, 0.f);
            cur = d;
            nv = ((const float4*)(nh + (size_t)d * C))[jq];
        }
        float4 sp = ((const float4*)(src_proj + (size_t)sidx[el] * C))[jq];

        float m0 = acc[i].x + sp.x, m1 = acc[i].y + sp.y;
        float m2 = acc[i].z + sp.z, m3 = acc[i].w + sp.w;

        float s0 = m0 + nv.x, s1 = m1 + nv.y, s2 = m2 + nv.z, s3 = m3 + nv.w;
        s0 = s0 > 0.f ? s0 : NEG * s0;
        s1 = s1 > 0.f ? s1 : NEG * s1;
        s2 = s2 > 0.f ? s2 : NEG * s2;
        s3 = s3 > 0.f ? s3 : NEG * s3;

        float e0 = __expf(s0), e1 = __expf(s1), e2 = __expf(s2), e3 = __expf(s3);

        nacc.x += e0 * m0; nacc.y += e1 * m1; nacc.z += e2 * m2; nacc.w += e3 * m3;
        dacc.x += e0;      dacc.y += e1;      dacc.z += e2;      dacc.w += e3;
    }
    {
        float* np = num + (size_t)cur * C + jq * 4;
        float* dp = den + (size_t)cur * C + jq * 4;
        atomicAdd(np + 0, nacc.x); atomicAdd(np + 1, nacc.y);
        atomicAdd(np + 2, nacc.z); atomicAdd(np + 3, nacc.w);
        atomicAdd(dp + 0, dacc.x); atomicAdd(dp + 1, dacc.y);
        atomicAdd(dp + 2, dacc.z); atomicAdd(dp + 3, dacc.w);
    }
}

// ---------------- finalize: out = num/den + bias  (den==0 -> bias, matches empty segment)
__global__ __launch_bounds__(256) void finalize_kernel(
    const float* __restrict__ num, const float* __restrict__ den,
    const float* __restrict__ bias, float* __restrict__ out)
{
    int i = blockIdx.x * 256 + threadIdx.x;      // float4 index
    float4 n = ((const float4*)num)[i];
    float4 d = ((const float4*)den)[i];
    float4 b = ((const float4*)bias)[i & 31];
    float4 r;
    r.x = (d.x != 0.f ? n.x / d.x : 0.f) + b.x;
    r.y = (d.y != 0.f ? n.y / d.y : 0.f) + b.y;
    r.z = (d.z != 0.f ? n.z / d.z : 0.f) + b.z;
    r.w = (d.w != 0.f ? n.w / d.w : 0.f) + b.w;
    ((float4*)out)[i] = r;
}

extern "C" void kernel_launch(void* const* d_in, const int* in_sizes, int n_in,
                              void* d_out, int out_size, void* d_ws, size_t ws_size,
                              hipStream_t stream) {
    const float* src_feat  = (const float*)d_in[0];
    const float* dst_feat  = (const float*)d_in[1];
    const float* edge_feat = (const float*)d_in[2];
    const float* W_src     = (const float*)d_in[3];   // [256][128]
    const float* W_dst     = (const float*)d_in[4];   // [128][128]
    const float* bias      = (const float*)d_in[5];   // [128]
    const int*   src_idx   = (const int*)d_in[6];
    const int*   dst_idx   = (const int*)d_in[7];
    float* out = (float*)d_out;                       // [50000][128] -> doubles as num accumulator

    const size_t NODEF = (size_t)NN * C;              // 6.4M floats

    float* ws       = (float*)d_ws;
    float* src_proj = ws;                             // 6.4M floats
    float* nh       = ws + NODEF;                     // 6.4M floats
    float* den      = ws + 2 * NODEF;                 // 6.4M floats
    int*   deg      = (int*)(ws + 3 * NODEF);         // NN ints
    int*   cursor   = deg + NN;                       // NN ints
    int*   elist    = cursor + NN;                    // EE ints   (total ~80.3 MB)

    float* num = out;  // accumulate numerator directly in d_out, finalize in place

    hipMemsetAsync(num, 0, NODEF * sizeof(float), stream);
    hipMemsetAsync(den, 0, NODEF * sizeof(float), stream);
    hipMemsetAsync(deg, 0, NN * sizeof(int), stream);

    // build dst-sorted edge list
    hist_kernel<<<(EE + 255) / 256, 256, 0, stream>>>(dst_idx, deg);
    scan_kernel<<<1, 1024, 0, stream>>>(deg, cursor);
    scatter_kernel<<<(EE + 255) / 256, 256, 0, stream>>>(dst_idx, cursor, elist);

    // node projections (independent of the sort)
    node_proj_kernel<<<dim3(NN / 8, 2), 256, 0, stream>>>(
        src_feat, dst_feat, W_src, W_dst, src_proj, nh);

    // sorted edge pass
    edge_kernel<<<EE / 64, 256, 0, stream>>>(
        edge_feat, W_src + 128 * 128, src_proj, nh, src_idx, dst_idx, elist, num, den);

    finalize_kernel<<<NODEF / 4 / 256, 256, 0, stream>>>(num, den, bias, out);
}